// Round 6
// baseline (461.465 us; speedup 1.0000x reference)
//
#include <hip/hip_runtime.h>
#include <hip/hip_cooperative_groups.h>
#include <math.h>

namespace cg = cooperative_groups;

#define L_TOT 4194304   // 2^22 upsampled samples
#define NFR   16384     // frames / f0 length
#define OUTN  4194048   // output length

// ---------- workspace layout (floats) ----------
// [0, L_TOT)                : cumsum tree levels 11..22 (packed at high end)
// [L_TOT, 2*L_TOT)          : pulse signal
// [2*L_TOT + 0,   +512)     : twiddle cos  (cos(2*pi*j/1024))
// [2*L_TOT + 512, +1024)    : twiddle sin
// [2*L_TOT + 2048,+2048+NFR): f0 = exp(log_f0)

__device__ __forceinline__ int lvl_off(int a) {
  return L_TOT - (L_TOT >> (a - 1));
}

__device__ __forceinline__ int swz(int e) {
  int h = (e >> 4) & 3, g = (e >> 6) & 3, f = (e >> 8) & 3;
  return e ^ (h * 5) ^ (g * 3) ^ ((f * 12) & 15);
}

__device__ __forceinline__ int dr4(int p) {
  return ((p & 3) << 8) | (((p >> 2) & 3) << 6) | (((p >> 4) & 3) << 4) |
         (((p >> 6) & 3) << 2) | ((p >> 8) & 3);
}

__device__ __forceinline__ float f0_up_val(const float* f0arr, int j) {
  float pos = __fadd_rn(__fmul_rn(__fadd_rn((float)j, 0.5f), 1.0f / 256.0f), -0.5f);
  pos = fminf(fmaxf(pos, 0.0f), 16383.0f);
  int lo = (int)pos;
  int hi = min(lo + 1, NFR - 1);
  float frac = __fadd_rn(pos, -(float)lo);
  float a = __fmul_rn(f0arr[lo], __fadd_rn(1.0f, -frac));
  float b = __fmul_rn(f0arr[hi], frac);
  return __fadd_rn(a, b);
}

__device__ __forceinline__ float f0_up_local(const float* Fl, int w0, int j) {
  float pos = __fadd_rn(__fmul_rn(__fadd_rn((float)j, 0.5f), 1.0f / 256.0f), -0.5f);
  pos = fminf(fmaxf(pos, 0.0f), 16383.0f);
  int lo = (int)pos;
  int hi = min(lo + 1, NFR - 1);
  float frac = __fadd_rn(pos, -(float)lo);
  float a = __fmul_rn(Fl[lo - w0], __fadd_rn(1.0f, -frac));
  float b = __fmul_rn(Fl[hi - w0], frac);
  return __fadd_rn(a, b);
}

__device__ float prefix_sum(const float* W, const float* f0arr, int m) {
  float acc = 0.0f;
  bool first = true;
  int pos = 0;
  for (int a = 22; a >= 1; --a) {
    if (m & (1 << a)) {
      float node = W[lvl_off(a) + (pos >> a)];
      acc = first ? node : __fadd_rn(acc, node);
      first = false;
      pos += (1 << a);
    }
  }
  if (m & 1) {
    float node = f0_up_val(f0arr, pos);
    acc = first ? node : __fadd_rn(acc, node);
  }
  return acc;
}

// ---------- ONE cooperative prep kernel: tables + zero-out + tree + top + pulse ----
// grid = 1024 blocks x 256 (co-resident: 4 blocks/CU needed, 8 fit by LDS).
// Phase A: tables, zero out, 2 tree chunks/block (levels 1..11).
// Phase B: block 0 builds levels 12..22.
// Phase C: pulse, 4096 samples/block (pre-R5 validated body, bit-exact).
__global__ __launch_bounds__(256) void prep_kernel(const float* __restrict__ logf0,
                                                   float* __restrict__ W,
                                                   float* __restrict__ out) {
  int tid = threadIdx.x;
  int bid = blockIdx.x;
  __shared__ union SU {
    struct { float A[2048]; float B[1024]; float Fl[10]; } t;   // tree phases
    struct { float Tl[510]; float P[4100]; } p;                 // pulse phase
  } U;

  float* twc = W + 2 * L_TOT;
  float* tws = twc + 512;
  float* f0arr = twc + 2048;

  // ---- Phase A: global tables (low blocks) ----
  if (bid < 2) {
    int g = bid * 256 + tid;
    double a = (double)g * 3.14159265358979323846 / 512.0;   // 2*pi*g/1024
    twc[g] = (float)cos(a);
    tws[g] = (float)sin(a);
  }
  if (bid >= 2 && bid < 66) {
    int g = (bid - 2) * 256 + tid;
    f0arr[g] = (float)exp((double)logf0[g]);   // bit-exact vs reference exp
  }
  // ---- Phase A: zero the output (replaces hipMemsetAsync launch) ----
  {
    int base_o = bid * 4096;
#pragma unroll
    for (int k = 0; k < 4; ++k) {
      int off = base_o + k * 1024 + tid * 4;
      if (off < OUTN) *(float4*)&out[off] = make_float4(0.f, 0.f, 0.f, 0.f);
    }
  }
  // ---- Phase A: two tree chunks (levels 1..11) per block ----
  for (int rep = 0; rep < 2; ++rep) {
    int base = (2 * bid + rep) * 2048;
    int w0 = (base >> 8) - 1;
    __syncthreads();   // U reuse across reps
    if (tid < 10) {
      int f = min(max(w0 + tid, 0), NFR - 1);
      U.t.Fl[tid] = (float)exp((double)logf0[f]);   // bit-exact vs f0arr
    }
    __syncthreads();
    for (int i = tid; i < 2048; i += 256) U.t.A[i] = f0_up_local(U.t.Fl, w0, base + i);
    __syncthreads();
    float* src = U.t.A;
    float* dst = U.t.B;
    int cnt = 1024;
    for (int a = 1; a <= 11; ++a) {
      int gbase = base >> a;
      for (int i = tid; i < cnt; i += 256) {
        float v = __fadd_rn(src[2 * i], src[2 * i + 1]);
        dst[i] = v;
        if (a == 11) W[lvl_off(11) + gbase + i] = v;
      }
      __syncthreads();
      float* tmp = src; src = dst; dst = tmp;
      cnt >>= 1;
    }
  }

  cg::this_grid().sync();

  // ---- Phase B: block 0 builds levels 12..22 ----
  if (bid == 0) {
    for (int i = tid; i < 2048; i += 256) U.t.A[i] = W[lvl_off(11) + i];
    __syncthreads();
    float* src = U.t.A;
    float* dst = U.t.B;
    int cnt = 1024;
    for (int a = 12; a <= 22; ++a) {
      for (int i = tid; i < cnt; i += 256) {
        float v = __fadd_rn(src[2 * i], src[2 * i + 1]);
        dst[i] = v;
        W[lvl_off(a) + i] = v;
      }
      __syncthreads();
      float* tmp = src; src = dst; dst = tmp;
      cnt >>= 1;
    }
  }

  cg::this_grid().sync();

  // ---- Phase C: impulse train, 4096 samples/block (validated R4-R8 body) ----
  {
    float* Tl = U.p.Tl;
    float* P = U.p.P;
    int base = bid * 4096;

    float v[16];
#pragma unroll
    for (int c = 0; c < 16; ++c) v[c] = f0_up_val(f0arr, base + 16 * tid + c);
    float s2[8], s4[4], s8[2];
#pragma unroll
    for (int j = 0; j < 8; ++j) s2[j] = __fadd_rn(v[2 * j], v[2 * j + 1]);
#pragma unroll
    for (int j = 0; j < 4; ++j) s4[j] = __fadd_rn(s2[2 * j], s2[2 * j + 1]);
    s8[0] = __fadd_rn(s4[0], s4[1]);
    s8[1] = __fadd_rn(s4[2], s4[3]);
    __syncthreads();   // U union: tree scratch -> pulse scratch
    Tl[tid] = __fadd_rn(s8[0], s8[1]);
    __syncthreads();
    if (tid < 128) Tl[256 + tid] = __fadd_rn(Tl[2 * tid], Tl[2 * tid + 1]);
    __syncthreads();
    if (tid < 64)  Tl[384 + tid] = __fadd_rn(Tl[256 + 2 * tid], Tl[256 + 2 * tid + 1]);
    __syncthreads();
    if (tid < 32)  Tl[448 + tid] = __fadd_rn(Tl[384 + 2 * tid], Tl[384 + 2 * tid + 1]);
    __syncthreads();
    if (tid < 16)  Tl[480 + tid] = __fadd_rn(Tl[448 + 2 * tid], Tl[448 + 2 * tid + 1]);
    __syncthreads();
    if (tid < 8)   Tl[496 + tid] = __fadd_rn(Tl[480 + 2 * tid], Tl[480 + 2 * tid + 1]);
    __syncthreads();
    if (tid < 4)   Tl[504 + tid] = __fadd_rn(Tl[496 + 2 * tid], Tl[496 + 2 * tid + 1]);
    __syncthreads();
    if (tid < 2)   Tl[508 + tid] = __fadd_rn(Tl[504 + 2 * tid], Tl[504 + 2 * tid + 1]);
    __syncthreads();

    float accT = 0.0f;
    bool firstT = true;
    {
      int pos = 0;
      for (int a = 22; a >= 12; --a) {
        if (base & (1 << a)) {
          float node = W[lvl_off(a) + (pos >> a)];
          accT = firstT ? node : __fadd_rn(accT, node);
          firstT = false;
          pos += (1 << a);
        }
      }
    }
    float accM = accT;
    bool firstM = firstT;
    {
      int rh = 16 * tid;
      int lpos = 0;
      for (int a = 11; a >= 4; --a) {
        if (rh & (1 << a)) {
          float node = Tl[512 - (512 >> (a - 4)) + (lpos >> a)];
          accM = firstM ? node : __fadd_rn(accM, node);
          firstM = false;
          lpos += (1 << a);
        }
      }
    }
    if (tid >= 1) P[16 * tid] = accM;
#pragma unroll
    for (int c = 1; c <= 15; ++c) {
      float acc = accM;
      bool first = firstM;
      int lp = 0;
      if (c & 8) { float n = s8[lp >> 3]; acc = first ? n : __fadd_rn(acc, n); first = false; lp += 8; }
      if (c & 4) { float n = s4[lp >> 2]; acc = first ? n : __fadd_rn(acc, n); first = false; lp += 4; }
      if (c & 2) { float n = s2[lp >> 1]; acc = first ? n : __fadd_rn(acc, n); first = false; lp += 2; }
      if (c & 1) { float n = v[lp];       acc = first ? n : __fadd_rn(acc, n); }
      P[16 * tid + c] = acc;
    }
    if (tid == 0) P[4096] = prefix_sum(W, f0arr, base + 4096);
    if (tid == 1) {
      int m2 = base + 4097;
      P[4097] = (m2 <= L_TOT) ? prefix_sum(W, f0arr, m2) : 0.0f;
    }
    __syncthreads();

    float o[16];
#pragma unroll
    for (int c = 0; c < 16; ++c) {
      int i = base + 16 * tid + c;
      float P1 = P[16 * tid + c + 1];
      float P2 = (i == L_TOT - 1) ? prefix_sum(W, f0arr, 1)
                                  : P[16 * tid + c + 2];
      float t1 = __fdiv_rn(P1, 24000.0f);
      float saw1 = __fadd_rn(t1, -floorf(t1));
      float t2 = __fdiv_rn(P2, 24000.0f);
      float saw2 = __fadd_rn(t2, -floorf(t2));
      float cc = __fdiv_rn(v[c], 24000.0f);
      o[c] = __fadd_rn(__fadd_rn(saw1, -saw2), cc);
    }
#pragma unroll
    for (int k = 0; k < 4; ++k)
      *(float4*)&W[L_TOT + base + 16 * tid + 4 * k] =
          make_float4(o[4 * k], o[4 * k + 1], o[4 * k + 2], o[4 * k + 3]);
  }
}

// ---------- in-place radix-4 butterflies, precomputed swizzled addresses ----------
template <int DIR>
__device__ __forceinline__ void bfly_dif(float2* F, int e0, int e1, int e2, int e3,
                                         float ur, float ui) {
  if (DIR < 0) ui = -ui;
  float2 x0 = F[e0], x1 = F[e1], x2 = F[e2], x3 = F[e3];
  float s0r = x0.x + x2.x, s0i = x0.y + x2.y;
  float s1r = x1.x + x3.x, s1i = x1.y + x3.y;
  float d0r = x0.x - x2.x, d0i = x0.y - x2.y;
  float ddr = x1.x - x3.x, ddi = x1.y - x3.y;
  float t3r = (DIR > 0) ? -ddi : ddi;
  float t3i = (DIR > 0) ? ddr : -ddr;
  float vr = ur * ur - ui * ui, vi = 2.0f * ur * ui;
  float w3r = ur * vr - ui * vi, w3i = ur * vi + ui * vr;
  F[e0] = make_float2(s0r + s1r, s0i + s1i);
  float a1r = d0r + t3r, a1i = d0i + t3i;
  F[e1] = make_float2(a1r * ur - a1i * ui, a1r * ui + a1i * ur);
  float a2r = s0r - s1r, a2i = s0i - s1i;
  F[e2] = make_float2(a2r * vr - a2i * vi, a2r * vi + a2i * vr);
  float a3r = d0r - t3r, a3i = d0i - t3i;
  F[e3] = make_float2(a3r * w3r - a3i * w3i, a3r * w3i + a3i * w3r);
  __syncthreads();
}

template <int DIR>
__device__ __forceinline__ void bfly_dit(float2* F, int e0, int e1, int e2, int e3,
                                         float ur, float ui) {
  if (DIR < 0) ui = -ui;
  float2 x0 = F[e0], x1 = F[e1], x2 = F[e2], x3 = F[e3];
  float vr = ur * ur - ui * ui, vi = 2.0f * ur * ui;
  float w3r = ur * vr - ui * vi, w3i = ur * vi + ui * vr;
  float b1r = x1.x * ur - x1.y * ui, b1i = x1.x * ui + x1.y * ur;
  float b2r = x2.x * vr - x2.y * vi, b2i = x2.x * vi + x2.y * vr;
  float b3r = x3.x * w3r - x3.y * w3i, b3i = x3.x * w3i + x3.y * w3r;
  float s0r = x0.x + b2r, s0i = x0.y + b2i;
  float d0r = x0.x - b2r, d0i = x0.y - b2i;
  float s1r = b1r + b3r, s1i = b1i + b3i;
  float ddr = b1r - b3r, ddi = b1i - b3i;
  float d1r = (DIR > 0) ? -ddi : ddi;
  float d1i = (DIR > 0) ? ddr : -ddr;
  F[e0] = make_float2(s0r + s1r, s0i + s1i);
  F[e1] = make_float2(d0r + d1r, d0i + d1i);
  F[e2] = make_float2(s0r - s1r, s0i - s1i);
  F[e3] = make_float2(d0r - d1r, d0i - d1i);
  __syncthreads();
}

__device__ __forceinline__ float hann_w(int i, const float2* T0) {
  int j = (i > 512) ? (1024 - i) : i;
  float c = (j <= 256) ? T0[j].x : -T0[512 - j].x;
  return 0.5f - 0.5f * c;
}

__device__ __forceinline__ float edge_scale(int t, const float2* T0) {
  int p = t + 512;
  int jmin = max(0, (p - 768) >> 8);
  int jmax = min(NFR - 1, p >> 8);
  float wsq = 0.0f;
  for (int j = jmin; j <= jmax; ++j) {
    float w = hann_w(p - 256 * j, T0);
    wsq += w * w;
  }
  return 1.5f / fmaxf(wsq, 1e-11f);
}

__device__ __forceinline__ void combine_one(int k, float An, const float2* F, float2* H) {
  int k2 = (1024 - k) & 1023;
  float2 z = F[swz(dr4(k))], mm = F[swz(dr4(k2))];
  float Ar = 0.5f * (z.x + mm.x), Ai = 0.5f * (z.y - mm.y);
  float Br = 0.5f * (z.y + mm.y), Bi = 0.5f * (mm.x - z.x);
  float2 h = H[k];
  H[k] = make_float2(Br * h.x - Bi * h.y + Ar * An,
                     Br * h.y + Bi * h.x + Ai * An);
}

// ---------- per-block fused kernel: TWO adjacent frames, 5 in-place FFTs ----------
__global__ __launch_bounds__(256) void column_kernel(
    const float* __restrict__ noise,
    const float* __restrict__ envn,
    const float* __restrict__ envp,
    const float* __restrict__ W,
    float* __restrict__ out) {
  __shared__ float2 F[1024];
  __shared__ float2 hA[513], hB[513];
  __shared__ float2 TW[341];
  int tid = threadIdx.x;
  int bid = blockIdx.x;
  int g = (bid & 7) * 1024 + (bid >> 3);
  int fA = 2 * g;
  const float* pulse = W + L_TOT;
  const float* gtab = W + 2 * L_TOT;
  const float2* T0 = TW;
  const float2* T1 = TW + 257;
  const float2* T2 = TW + 321;
  const float2* T3 = TW + 337;

  for (int i = tid; i < 341; i += 256) {
    int e;
    if (i < 257) e = i;
    else if (i < 321) e = (i - 257) << 2;
    else if (i < 337) e = (i - 321) << 4;
    else e = (i - 337) << 6;
    TW[i] = make_float2(gtab[e], gtab[512 + e]);
  }
  for (int k = tid; k < 513; k += 256) {
    float2 e = *(const float2*)&envp[k * NFR + fA];
    hA[k] = e;
  }

  int a00 = swz(tid), a01 = swz(tid + 256), a02 = swz(tid + 512), a03 = swz(tid + 768);
  int b1_ = ((tid >> 6) << 8) | (tid & 63);
  int a10 = swz(b1_), a11 = swz(b1_ + 64), a12 = swz(b1_ + 128), a13 = swz(b1_ + 192);
  int b2_ = ((tid >> 4) << 6) | (tid & 15);
  int a20 = swz(b2_), a21 = swz(b2_ + 16), a22 = swz(b2_ + 32), a23 = swz(b2_ + 48);
  int b3_ = ((tid >> 2) << 4) | (tid & 3);
  int a30 = swz(b3_), a31 = swz(b3_ + 4), a32 = swz(b3_ + 8), a33 = swz(b3_ + 12);
  int q_ = tid << 2;
  int a40 = swz(q_), a41 = swz(q_ + 1), a42 = swz(q_ + 2), a43 = swz(q_ + 3);
  __syncthreads();

  // ---- (1) packed cepstrum ----
  F[a00] = hA[tid];
  F[a01] = hA[tid + 256];
  F[a02] = (tid == 0) ? hA[512] : hA[512 - tid];
  F[a03] = hA[256 - tid];
  __syncthreads();
  { float2 t_ = T0[tid];      bfly_dif<+1>(F, a00, a01, a02, a03, t_.x, t_.y); }
  { float2 t_ = T1[tid & 63]; bfly_dif<+1>(F, a10, a11, a12, a13, t_.x, t_.y); }
  { float2 t_ = T2[tid & 15]; bfly_dif<+1>(F, a20, a21, a22, a23, t_.x, t_.y); }
  { float2 t_ = T3[tid & 3];  bfly_dif<+1>(F, a30, a31, a32, a33, t_.x, t_.y); }
  // register phase: DIF s4 + cep fold + DIT<-1> s0 on thread-local {4t..4t+3}
  {
    int drt = ((tid & 3) << 6) | (((tid >> 2) & 3) << 4) |
              (((tid >> 4) & 3) << 2) | ((tid >> 6) & 3);   // dr4(4*tid)
    float2 x0 = F[a40], x1 = F[a41], x2 = F[a42], x3 = F[a43];
    float s0r = x0.x + x2.x, s0i = x0.y + x2.y;
    float s1r = x1.x + x3.x, s1i = x1.y + x3.y;
    float d0r = x0.x - x2.x, d0i = x0.y - x2.y;
    float ddr = x1.x - x3.x, ddi = x1.y - x3.y;
    float y0r = s0r + s1r, y0i = s0i + s1i;       // bin drt
    float y1r = d0r - ddi, y1i = d0i + ddr;       // bin drt+256
    float y2r = s0r - s1r, y2i = s0i - s1i;       // bin drt+512
    float sc0 = (drt == 0) ? (1.0f / 1024.0f) : (2.0f / 1024.0f);
    float sc2 = (drt == 0) ? (1.0f / 1024.0f) : 0.0f;
    y0r *= sc0; y0i *= sc0;
    y1r *= (2.0f / 1024.0f); y1i *= (2.0f / 1024.0f);
    y2r *= sc2; y2i *= sc2;
    float S0r = y0r + y2r, S0i = y0i + y2i;
    float D0r = y0r - y2r, D0i = y0i - y2i;
    float D1r = y1i, D1i = -y1r;                  // DIR=-1, dd=y1
    F[a40] = make_float2(S0r + y1r, S0i + y1i);
    F[a41] = make_float2(D0r + D1r, D0i + D1i);
    F[a42] = make_float2(S0r - y1r, S0i - y1i);
    F[a43] = make_float2(D0r - D1r, D0i - D1i);
  }
  __syncthreads();
  { float2 t_ = T3[tid & 3];  bfly_dit<-1>(F, a30, a31, a32, a33, t_.x, t_.y); }
  { float2 t_ = T2[tid & 15]; bfly_dit<-1>(F, a20, a21, a22, a23, t_.x, t_.y); }
  { float2 t_ = T1[tid & 63]; bfly_dit<-1>(F, a10, a11, a12, a13, t_.x, t_.y); }
  { float2 t_ = T0[tid];      bfly_dit<-1>(F, a00, a01, a02, a03, t_.x, t_.y); }
  // hermitian unpack; H=exp
  {
    int k2 = (1024 - tid) & 1023;
    float2 z = F[a00], mm = F[swz(k2)];
    float GAr = 0.5f * (z.x + mm.x), GAi = 0.5f * (z.y - mm.y);
    float GBr = 0.5f * (z.y + mm.y), GBi = 0.5f * (mm.x - z.x);
    float er = expf(GAr);
    float si, co;
    sincosf(GAi, &si, &co);
    hA[tid] = make_float2(er * co, er * si);
    er = expf(GBr);
    sincosf(GBi, &si, &co);
    hB[tid] = make_float2(er * co, er * si);

    z = F[a01]; mm = F[swz(768 - tid)];
    GAr = 0.5f * (z.x + mm.x); GAi = 0.5f * (z.y - mm.y);
    GBr = 0.5f * (z.y + mm.y); GBi = 0.5f * (mm.x - z.x);
    er = expf(GAr);
    sincosf(GAi, &si, &co);
    hA[tid + 256] = make_float2(er * co, er * si);
    er = expf(GBr);
    sincosf(GBi, &si, &co);
    hB[tid + 256] = make_float2(er * co, er * si);

    if (tid == 0) {
      z = F[a02];
      GAr = 0.5f * (z.x + z.x); GAi = 0.0f;
      GBr = 0.5f * (z.y + z.y); GBi = 0.0f;
      er = expf(GAr);
      sincosf(GAi, &si, &co);
      hA[512] = make_float2(er * co, er * si);
      er = expf(GBr);
      sincosf(GBi, &si, &co);
      hB[512] = make_float2(er * co, er * si);
    }
  }
  __syncthreads();

  // ---- (3) frame A ----
#define PACK_FRAME(QOFF, J, ADDR)                                      \
  {                                                                    \
    int i = tid + 256 * (J);                                           \
    int q = (QOFF) + i;                                                \
    if (q < 0) q = -q;                                                 \
    else if (q >= L_TOT) q = 2 * L_TOT - 2 - q;                        \
    float wv = hann_w(i, T0);                                          \
    F[ADDR] = make_float2(noise[q] * wv, pulse[q] * wv);               \
  }
  PACK_FRAME(256 * fA - 256, 0, a00)
  PACK_FRAME(256 * fA - 256, 1, a01)
  PACK_FRAME(256 * fA - 256, 2, a02)
  PACK_FRAME(256 * fA - 256, 3, a03)
  __syncthreads();
  { float2 t_ = T0[tid];      bfly_dif<-1>(F, a00, a01, a02, a03, t_.x, t_.y); }
  { float2 t_ = T1[tid & 63]; bfly_dif<-1>(F, a10, a11, a12, a13, t_.x, t_.y); }
  { float2 t_ = T2[tid & 15]; bfly_dif<-1>(F, a20, a21, a22, a23, t_.x, t_.y); }
  { float2 t_ = T3[tid & 3];  bfly_dif<-1>(F, a30, a31, a32, a33, t_.x, t_.y); }
  bfly_dif<-1>(F, a40, a41, a42, a43, 1.0f, 0.0f);
  float2 eA0 = *(const float2*)&envn[tid * NFR + fA];
  combine_one(tid, expf(eA0.x), F, hA);
  float2 eA1 = *(const float2*)&envn[(tid + 256) * NFR + fA];
  combine_one(tid + 256, expf(eA1.x), F, hA);
  float2 eA2 = make_float2(0.0f, 0.0f);
  if (tid == 0) {
    eA2 = *(const float2*)&envn[512 * NFR + fA];
    combine_one(512, expf(eA2.x), F, hA);
  }
  __syncthreads();

  // ---- (4) frame B ----
  PACK_FRAME(256 * fA, 0, a00)
  PACK_FRAME(256 * fA, 1, a01)
  PACK_FRAME(256 * fA, 2, a02)
  PACK_FRAME(256 * fA, 3, a03)
  __syncthreads();
  { float2 t_ = T0[tid];      bfly_dif<-1>(F, a00, a01, a02, a03, t_.x, t_.y); }
  { float2 t_ = T1[tid & 63]; bfly_dif<-1>(F, a10, a11, a12, a13, t_.x, t_.y); }
  { float2 t_ = T2[tid & 15]; bfly_dif<-1>(F, a20, a21, a22, a23, t_.x, t_.y); }
  { float2 t_ = T3[tid & 3];  bfly_dif<-1>(F, a30, a31, a32, a33, t_.x, t_.y); }
  bfly_dif<-1>(F, a40, a41, a42, a43, 1.0f, 0.0f);
  combine_one(tid, expf(eA0.y), F, hB);
  combine_one(tid + 256, expf(eA1.y), F, hB);
  if (tid == 0) combine_one(512, expf(eA2.y), F, hB);
  __syncthreads();

  // ---- (5) packed hermitian inverse ----
#pragma unroll
  for (int j = 0; j < 4; ++j) {
    int i = tid + 256 * j;
    float2 zv;
    if (i <= 512) {
      zv = make_float2(hA[i].x - hB[i].y, hA[i].y + hB[i].x);
    } else {
      int jj = 1024 - i;
      zv = make_float2(hA[jj].x + hB[jj].y, hB[jj].x - hA[jj].y);
    }
    F[swz(dr4(i))] = zv;
  }
  __syncthreads();
  bfly_dit<+1>(F, a40, a41, a42, a43, 1.0f, 0.0f);
  { float2 t_ = T3[tid & 3];  bfly_dit<+1>(F, a30, a31, a32, a33, t_.x, t_.y); }
  { float2 t_ = T2[tid & 15]; bfly_dit<+1>(F, a20, a21, a22, a23, t_.x, t_.y); }
  { float2 t_ = T1[tid & 63]; bfly_dit<+1>(F, a10, a11, a12, a13, t_.x, t_.y); }
  { float2 t_ = T0[tid];      bfly_dit<+1>(F, a00, a01, a02, a03, t_.x, t_.y); }
  // fused OLA + inline edge scaling
  const float scl = 1.0f / 1536.0f;
  {
    float2 f0v = F[a00], f1v = F[a01], f2v = F[a02], f3v = F[a03];
    float hw0 = hann_w(tid, T0) * scl;
    float hw1 = hann_w(tid + 256, T0) * scl;
    float hw2 = hann_w(tid + 512, T0) * scl;
    float hw3 = hann_w(tid + 768, T0) * scl;
    int tb = 256 * fA - 512 + tid;
    float val;
    int t;
    t = tb;
    val = f0v.x * hw0;
    if (t >= 0) {
      if (t < 256) val *= edge_scale(t, T0);
      atomicAdd(&out[t], val);
    }
    t = tb + 256;
    val = f1v.x * hw1 + f0v.y * hw0;
    if (t >= 0 && t < OUTN) {
      if (t < 256 || t >= OUTN - 256) val *= edge_scale(t, T0);
      atomicAdd(&out[t], val);
    }
    t = tb + 512;
    val = f2v.x * hw2 + f1v.y * hw1;
    if (t < OUTN) {
      if (t < 256 || t >= OUTN - 256) val *= edge_scale(t, T0);
      atomicAdd(&out[t], val);
    }
    t = tb + 768;
    val = f3v.x * hw3 + f2v.y * hw2;
    if (t < OUTN) {
      if (t >= OUTN - 256) val *= edge_scale(t, T0);
      atomicAdd(&out[t], val);
    }
    t = tb + 1024;
    val = f3v.y * hw3;
    if (t < OUTN) {
      if (t >= OUTN - 256) val *= edge_scale(t, T0);
      atomicAdd(&out[t], val);
    }
  }
#undef PACK_FRAME
}

extern "C" void kernel_launch(void* const* d_in, const int* in_sizes, int n_in,
                              void* d_out, int out_size, void* d_ws, size_t ws_size,
                              hipStream_t stream) {
  const float* logf0 = (const float*)d_in[0];
  const float* envn  = (const float*)d_in[1];
  const float* envp  = (const float*)d_in[2];
  const float* noise = (const float*)d_in[3];
  float* out = (float*)d_out;
  float* W = (float*)d_ws;

  void* args[] = {(void*)&logf0, (void*)&W, (void*)&out};
  hipLaunchCooperativeKernel((const void*)prep_kernel, dim3(1024), dim3(256),
                             args, 0, stream);
  column_kernel<<<dim3(NFR / 2), dim3(256), 0, stream>>>(noise, envn, envp, W, out);
}

// Round 7
// 226.810 us; speedup vs baseline: 2.0346x; 2.0346x over previous
//
#include <hip/hip_runtime.h>
#include <math.h>

#define L_TOT 4194304   // 2^22 upsampled samples
#define NFR   16384     // frames / f0 length
#define OUTN  4194048   // output length

// ---------- workspace layout (floats) ----------
// [0, L_TOT)                : cumsum tree levels 11..22 (packed at high end)
// [L_TOT, 2*L_TOT)          : pulse signal
// [2*L_TOT + 0,   +512)     : twiddle cos  (cos(2*pi*j/1024))
// [2*L_TOT + 512, +1024)    : twiddle sin
// [2*L_TOT + 2048,+2048+NFR): f0 = exp(log_f0)

__device__ __forceinline__ int lvl_off(int a) {
  return L_TOT - (L_TOT >> (a - 1));
}

__device__ __forceinline__ int swz(int e) {
  int h = (e >> 4) & 3, g = (e >> 6) & 3, f = (e >> 8) & 3;
  return e ^ (h * 5) ^ (g * 3) ^ ((f * 12) & 15);
}

__device__ __forceinline__ int dr4(int p) {
  return ((p & 3) << 8) | (((p >> 2) & 3) << 6) | (((p >> 4) & 3) << 4) |
         (((p >> 6) & 3) << 2) | ((p >> 8) & 3);
}

__device__ __forceinline__ float f0_up_val(const float* f0arr, int j) {
  float pos = __fadd_rn(__fmul_rn(__fadd_rn((float)j, 0.5f), 1.0f / 256.0f), -0.5f);
  pos = fminf(fmaxf(pos, 0.0f), 16383.0f);
  int lo = (int)pos;
  int hi = min(lo + 1, NFR - 1);
  float frac = __fadd_rn(pos, -(float)lo);
  float a = __fmul_rn(f0arr[lo], __fadd_rn(1.0f, -frac));
  float b = __fmul_rn(f0arr[hi], frac);
  return __fadd_rn(a, b);
}

__device__ __forceinline__ float f0_up_local(const float* Fl, int w0, int j) {
  float pos = __fadd_rn(__fmul_rn(__fadd_rn((float)j, 0.5f), 1.0f / 256.0f), -0.5f);
  pos = fminf(fmaxf(pos, 0.0f), 16383.0f);
  int lo = (int)pos;
  int hi = min(lo + 1, NFR - 1);
  float frac = __fadd_rn(pos, -(float)lo);
  float a = __fmul_rn(Fl[lo - w0], __fadd_rn(1.0f, -frac));
  float b = __fmul_rn(Fl[hi - w0], frac);
  return __fadd_rn(a, b);
}

__device__ float prefix_sum(const float* W, const float* f0arr, int m) {
  float acc = 0.0f;
  bool first = true;
  int pos = 0;
  for (int a = 22; a >= 1; --a) {
    if (m & (1 << a)) {
      float node = W[lvl_off(a) + (pos >> a)];
      acc = first ? node : __fadd_rn(acc, node);
      first = false;
      pos += (1 << a);
    }
  }
  if (m & 1) {
    float node = f0_up_val(f0arr, pos);
    acc = first ? node : __fadd_rn(acc, node);
  }
  return acc;
}

// ---------- cumsum tree levels 1..11 + table init + out zeroing ----------
// R6 lesson: cooperative grid.sync costs ~100-200us on MI355X (cross-XCD
// contended barrier) -- separate launches are far cheaper. This kernel instead
// absorbs the init_tables and memset launches (no ordering hazard: later
// kernels read these only after this launch completes).
__global__ __launch_bounds__(256) void tree_kernel(const float* __restrict__ logf0,
                                                   float* __restrict__ W,
                                                   float* __restrict__ out) {
  int tid = threadIdx.x;
  int bid = blockIdx.x;
  // global tables (low blocks)
  if (bid < 2) {
    int g = bid * 256 + tid;
    double a = (double)g * 3.14159265358979323846 / 512.0;   // 2*pi*g/1024
    W[2 * L_TOT + g] = (float)cos(a);
    W[2 * L_TOT + 512 + g] = (float)sin(a);
  }
  if (bid >= 2 && bid < 66) {
    int g = (bid - 2) * 256 + tid;
    W[2 * L_TOT + 2048 + g] = (float)exp((double)logf0[g]);  // bit-exact
  }
  // zero the output (replaces hipMemsetAsync launch): 2048 floats/block
  {
    int base_o = bid * 2048;
#pragma unroll
    for (int k = 0; k < 2; ++k) {
      int off = base_o + k * 1024 + tid * 4;
      if (off < OUTN) *(float4*)&out[off] = make_float4(0.f, 0.f, 0.f, 0.f);
    }
  }
  // tree chunk (levels 1..11)
  __shared__ float Fl[10];
  __shared__ float A[2048];
  __shared__ float B[1024];
  int base = bid * 2048;
  int w0 = (base >> 8) - 1;
  if (tid < 10) {
    int f = min(max(w0 + tid, 0), NFR - 1);
    Fl[tid] = (float)exp((double)logf0[f]);   // bit-exact vs f0arr
  }
  __syncthreads();
  for (int i = tid; i < 2048; i += 256) A[i] = f0_up_local(Fl, w0, base + i);
  __syncthreads();
  float* src = A;
  float* dst = B;
  int cnt = 1024;
  for (int a = 1; a <= 11; ++a) {
    int gbase = base >> a;
    for (int i = tid; i < cnt; i += 256) {
      float v = __fadd_rn(src[2 * i], src[2 * i + 1]);
      dst[i] = v;
      if (a == 11) W[lvl_off(11) + gbase + i] = v;
    }
    __syncthreads();
    float* tmp = src; src = dst; dst = tmp;
    cnt >>= 1;
  }
}

// ---------- cumsum tree levels 12..22 (pure; R5's prefix tail removed) ----------
__global__ __launch_bounds__(256) void tree_top_kernel(float* W) {
  __shared__ float A[2048];
  __shared__ float B[1024];
  int tid = threadIdx.x;
  for (int i = tid; i < 2048; i += 256) A[i] = W[lvl_off(11) + i];
  __syncthreads();
  float* src = A;
  float* dst = B;
  int cnt = 1024;
  for (int a = 12; a <= 22; ++a) {
    for (int i = tid; i < cnt; i += 256) {
      float v = __fadd_rn(src[2 * i], src[2 * i + 1]);
      dst[i] = v;
      W[lvl_off(a) + i] = v;
    }
    __syncthreads();
    float* tmp = src; src = dst; dst = tmp;
    cnt >>= 1;
  }
}

// ---------- impulse train v3 (self-contained boundary prefixes; bit-exact) ----------
__global__ __launch_bounds__(256) void pulse_kernel(float* W) {
  const float* f0arr = W + 2 * L_TOT + 2048;
  __shared__ float Tl[510];
  __shared__ float P[4100];
  int tid = threadIdx.x;
  int base = blockIdx.x * 4096;

  float v[16];
#pragma unroll
  for (int c = 0; c < 16; ++c) v[c] = f0_up_val(f0arr, base + 16 * tid + c);
  float s2[8], s4[4], s8[2];
#pragma unroll
  for (int j = 0; j < 8; ++j) s2[j] = __fadd_rn(v[2 * j], v[2 * j + 1]);
#pragma unroll
  for (int j = 0; j < 4; ++j) s4[j] = __fadd_rn(s2[2 * j], s2[2 * j + 1]);
  s8[0] = __fadd_rn(s4[0], s4[1]);
  s8[1] = __fadd_rn(s4[2], s4[3]);
  Tl[tid] = __fadd_rn(s8[0], s8[1]);
  __syncthreads();
  if (tid < 128) Tl[256 + tid] = __fadd_rn(Tl[2 * tid], Tl[2 * tid + 1]);
  __syncthreads();
  if (tid < 64)  Tl[384 + tid] = __fadd_rn(Tl[256 + 2 * tid], Tl[256 + 2 * tid + 1]);
  __syncthreads();
  if (tid < 32)  Tl[448 + tid] = __fadd_rn(Tl[384 + 2 * tid], Tl[384 + 2 * tid + 1]);
  __syncthreads();
  if (tid < 16)  Tl[480 + tid] = __fadd_rn(Tl[448 + 2 * tid], Tl[448 + 2 * tid + 1]);
  __syncthreads();
  if (tid < 8)   Tl[496 + tid] = __fadd_rn(Tl[480 + 2 * tid], Tl[480 + 2 * tid + 1]);
  __syncthreads();
  if (tid < 4)   Tl[504 + tid] = __fadd_rn(Tl[496 + 2 * tid], Tl[496 + 2 * tid + 1]);
  __syncthreads();
  if (tid < 2)   Tl[508 + tid] = __fadd_rn(Tl[504 + 2 * tid], Tl[504 + 2 * tid + 1]);
  __syncthreads();

  float accT = 0.0f;
  bool firstT = true;
  {
    int pos = 0;
    for (int a = 22; a >= 12; --a) {
      if (base & (1 << a)) {
        float node = W[lvl_off(a) + (pos >> a)];
        accT = firstT ? node : __fadd_rn(accT, node);
        firstT = false;
        pos += (1 << a);
      }
    }
  }
  float accM = accT;
  bool firstM = firstT;
  {
    int rh = 16 * tid;
    int lpos = 0;
    for (int a = 11; a >= 4; --a) {
      if (rh & (1 << a)) {
        float node = Tl[512 - (512 >> (a - 4)) + (lpos >> a)];
        accM = firstM ? node : __fadd_rn(accM, node);
        firstM = false;
        lpos += (1 << a);
      }
    }
  }
  if (tid >= 1) P[16 * tid] = accM;
#pragma unroll
  for (int c = 1; c <= 15; ++c) {
    float acc = accM;
    bool first = firstM;
    int lp = 0;
    if (c & 8) { float n = s8[lp >> 3]; acc = first ? n : __fadd_rn(acc, n); first = false; lp += 8; }
    if (c & 4) { float n = s4[lp >> 2]; acc = first ? n : __fadd_rn(acc, n); first = false; lp += 4; }
    if (c & 2) { float n = s2[lp >> 1]; acc = first ? n : __fadd_rn(acc, n); first = false; lp += 2; }
    if (c & 1) { float n = v[lp];       acc = first ? n : __fadd_rn(acc, n); }
    P[16 * tid + c] = acc;
  }
  if (tid == 0) P[4096] = prefix_sum(W, f0arr, base + 4096);
  if (tid == 1) {
    int m2 = base + 4097;
    P[4097] = (m2 <= L_TOT) ? prefix_sum(W, f0arr, m2) : 0.0f;
  }
  __syncthreads();

  float o[16];
#pragma unroll
  for (int c = 0; c < 16; ++c) {
    int i = base + 16 * tid + c;
    float P1 = P[16 * tid + c + 1];
    float P2 = (i == L_TOT - 1) ? prefix_sum(W, f0arr, 1)
                                : P[16 * tid + c + 2];
    float t1 = __fdiv_rn(P1, 24000.0f);
    float saw1 = __fadd_rn(t1, -floorf(t1));
    float t2 = __fdiv_rn(P2, 24000.0f);
    float saw2 = __fadd_rn(t2, -floorf(t2));
    float cc = __fdiv_rn(v[c], 24000.0f);
    o[c] = __fadd_rn(__fadd_rn(saw1, -saw2), cc);
  }
#pragma unroll
  for (int k = 0; k < 4; ++k)
    *(float4*)&W[L_TOT + base + 16 * tid + 4 * k] =
        make_float4(o[4 * k], o[4 * k + 1], o[4 * k + 2], o[4 * k + 3]);
}

// ---------- in-place radix-4 butterflies, precomputed swizzled addresses ----------
template <int DIR>
__device__ __forceinline__ void bfly_dif(float2* F, int e0, int e1, int e2, int e3,
                                         float ur, float ui) {
  if (DIR < 0) ui = -ui;
  float2 x0 = F[e0], x1 = F[e1], x2 = F[e2], x3 = F[e3];
  float s0r = x0.x + x2.x, s0i = x0.y + x2.y;
  float s1r = x1.x + x3.x, s1i = x1.y + x3.y;
  float d0r = x0.x - x2.x, d0i = x0.y - x2.y;
  float ddr = x1.x - x3.x, ddi = x1.y - x3.y;
  float t3r = (DIR > 0) ? -ddi : ddi;
  float t3i = (DIR > 0) ? ddr : -ddr;
  float vr = ur * ur - ui * ui, vi = 2.0f * ur * ui;
  float w3r = ur * vr - ui * vi, w3i = ur * vi + ui * vr;
  F[e0] = make_float2(s0r + s1r, s0i + s1i);
  float a1r = d0r + t3r, a1i = d0i + t3i;
  F[e1] = make_float2(a1r * ur - a1i * ui, a1r * ui + a1i * ur);
  float a2r = s0r - s1r, a2i = s0i - s1i;
  F[e2] = make_float2(a2r * vr - a2i * vi, a2r * vi + a2i * vr);
  float a3r = d0r - t3r, a3i = d0i - t3i;
  F[e3] = make_float2(a3r * w3r - a3i * w3i, a3r * w3i + a3i * w3r);
  __syncthreads();
}

template <int DIR>
__device__ __forceinline__ void bfly_dit(float2* F, int e0, int e1, int e2, int e3,
                                         float ur, float ui) {
  if (DIR < 0) ui = -ui;
  float2 x0 = F[e0], x1 = F[e1], x2 = F[e2], x3 = F[e3];
  float vr = ur * ur - ui * ui, vi = 2.0f * ur * ui;
  float w3r = ur * vr - ui * vi, w3i = ur * vi + ui * vr;
  float b1r = x1.x * ur - x1.y * ui, b1i = x1.x * ui + x1.y * ur;
  float b2r = x2.x * vr - x2.y * vi, b2i = x2.x * vi + x2.y * vr;
  float b3r = x3.x * w3r - x3.y * w3i, b3i = x3.x * w3i + x3.y * w3r;
  float s0r = x0.x + b2r, s0i = x0.y + b2i;
  float d0r = x0.x - b2r, d0i = x0.y - b2i;
  float s1r = b1r + b3r, s1i = b1i + b3i;
  float ddr = b1r - b3r, ddi = b1i - b3i;
  float d1r = (DIR > 0) ? -ddi : ddi;
  float d1i = (DIR > 0) ? ddr : -ddr;
  F[e0] = make_float2(s0r + s1r, s0i + s1i);
  F[e1] = make_float2(d0r + d1r, d0i + d1i);
  F[e2] = make_float2(s0r - s1r, s0i - s1i);
  F[e3] = make_float2(d0r - d1r, d0i - d1i);
  __syncthreads();
}

__device__ __forceinline__ float hann_w(int i, const float2* T0) {
  int j = (i > 512) ? (1024 - i) : i;
  float c = (j <= 256) ? T0[j].x : -T0[512 - j].x;
  return 0.5f - 0.5f * c;
}

__device__ __forceinline__ float edge_scale(int t, const float2* T0) {
  int p = t + 512;
  int jmin = max(0, (p - 768) >> 8);
  int jmax = min(NFR - 1, p >> 8);
  float wsq = 0.0f;
  for (int j = jmin; j <= jmax; ++j) {
    float w = hann_w(p - 256 * j, T0);
    wsq += w * w;
  }
  return 1.5f / fmaxf(wsq, 1e-11f);
}

__device__ __forceinline__ void combine_one(int k, float An, const float2* F, float2* H) {
  int k2 = (1024 - k) & 1023;
  float2 z = F[swz(dr4(k))], mm = F[swz(dr4(k2))];
  float Ar = 0.5f * (z.x + mm.x), Ai = 0.5f * (z.y - mm.y);
  float Br = 0.5f * (z.y + mm.y), Bi = 0.5f * (mm.x - z.x);
  float2 h = H[k];
  H[k] = make_float2(Br * h.x - Bi * h.y + Ar * An,
                     Br * h.y + Bi * h.x + Ai * An);
}

// ---------- per-block fused kernel: TWO adjacent frames, 5 in-place FFTs ----------
__global__ __launch_bounds__(256) void column_kernel(
    const float* __restrict__ noise,
    const float* __restrict__ envn,
    const float* __restrict__ envp,
    const float* __restrict__ W,
    float* __restrict__ out) {
  __shared__ float2 F[1024];
  __shared__ float2 hA[513], hB[513];
  __shared__ float2 TW[341];
  int tid = threadIdx.x;
  int bid = blockIdx.x;
  int g = (bid & 7) * 1024 + (bid >> 3);
  int fA = 2 * g;
  const float* pulse = W + L_TOT;
  const float* gtab = W + 2 * L_TOT;
  const float2* T0 = TW;
  const float2* T1 = TW + 257;
  const float2* T2 = TW + 321;
  const float2* T3 = TW + 337;

  for (int i = tid; i < 341; i += 256) {
    int e;
    if (i < 257) e = i;
    else if (i < 321) e = (i - 257) << 2;
    else if (i < 337) e = (i - 321) << 4;
    else e = (i - 337) << 6;
    TW[i] = make_float2(gtab[e], gtab[512 + e]);
  }
  for (int k = tid; k < 513; k += 256) {
    float2 e = *(const float2*)&envp[k * NFR + fA];
    hA[k] = e;
  }

  int a00 = swz(tid), a01 = swz(tid + 256), a02 = swz(tid + 512), a03 = swz(tid + 768);
  int b1_ = ((tid >> 6) << 8) | (tid & 63);
  int a10 = swz(b1_), a11 = swz(b1_ + 64), a12 = swz(b1_ + 128), a13 = swz(b1_ + 192);
  int b2_ = ((tid >> 4) << 6) | (tid & 15);
  int a20 = swz(b2_), a21 = swz(b2_ + 16), a22 = swz(b2_ + 32), a23 = swz(b2_ + 48);
  int b3_ = ((tid >> 2) << 4) | (tid & 3);
  int a30 = swz(b3_), a31 = swz(b3_ + 4), a32 = swz(b3_ + 8), a33 = swz(b3_ + 12);
  int q_ = tid << 2;
  int a40 = swz(q_), a41 = swz(q_ + 1), a42 = swz(q_ + 2), a43 = swz(q_ + 3);
  __syncthreads();

  // ---- (1) packed cepstrum ----
  F[a00] = hA[tid];
  F[a01] = hA[tid + 256];
  F[a02] = (tid == 0) ? hA[512] : hA[512 - tid];
  F[a03] = hA[256 - tid];
  __syncthreads();
  { float2 t_ = T0[tid];      bfly_dif<+1>(F, a00, a01, a02, a03, t_.x, t_.y); }
  { float2 t_ = T1[tid & 63]; bfly_dif<+1>(F, a10, a11, a12, a13, t_.x, t_.y); }
  { float2 t_ = T2[tid & 15]; bfly_dif<+1>(F, a20, a21, a22, a23, t_.x, t_.y); }
  { float2 t_ = T3[tid & 3];  bfly_dif<+1>(F, a30, a31, a32, a33, t_.x, t_.y); }
  // register phase: DIF s4 + cep fold + DIT<-1> s0 on thread-local {4t..4t+3}
  {
    int drt = ((tid & 3) << 6) | (((tid >> 2) & 3) << 4) |
              (((tid >> 4) & 3) << 2) | ((tid >> 6) & 3);   // dr4(4*tid)
    float2 x0 = F[a40], x1 = F[a41], x2 = F[a42], x3 = F[a43];
    float s0r = x0.x + x2.x, s0i = x0.y + x2.y;
    float s1r = x1.x + x3.x, s1i = x1.y + x3.y;
    float d0r = x0.x - x2.x, d0i = x0.y - x2.y;
    float ddr = x1.x - x3.x, ddi = x1.y - x3.y;
    float y0r = s0r + s1r, y0i = s0i + s1i;       // bin drt
    float y1r = d0r - ddi, y1i = d0i + ddr;       // bin drt+256
    float y2r = s0r - s1r, y2i = s0i - s1i;       // bin drt+512
    float sc0 = (drt == 0) ? (1.0f / 1024.0f) : (2.0f / 1024.0f);
    float sc2 = (drt == 0) ? (1.0f / 1024.0f) : 0.0f;
    y0r *= sc0; y0i *= sc0;
    y1r *= (2.0f / 1024.0f); y1i *= (2.0f / 1024.0f);
    y2r *= sc2; y2i *= sc2;
    float S0r = y0r + y2r, S0i = y0i + y2i;
    float D0r = y0r - y2r, D0i = y0i - y2i;
    float D1r = y1i, D1i = -y1r;                  // DIR=-1, dd=y1
    F[a40] = make_float2(S0r + y1r, S0i + y1i);
    F[a41] = make_float2(D0r + D1r, D0i + D1i);
    F[a42] = make_float2(S0r - y1r, S0i - y1i);
    F[a43] = make_float2(D0r - D1r, D0i - D1i);
  }
  __syncthreads();
  { float2 t_ = T3[tid & 3];  bfly_dit<-1>(F, a30, a31, a32, a33, t_.x, t_.y); }
  { float2 t_ = T2[tid & 15]; bfly_dit<-1>(F, a20, a21, a22, a23, t_.x, t_.y); }
  { float2 t_ = T1[tid & 63]; bfly_dit<-1>(F, a10, a11, a12, a13, t_.x, t_.y); }
  { float2 t_ = T0[tid];      bfly_dit<-1>(F, a00, a01, a02, a03, t_.x, t_.y); }
  // hermitian unpack; H=exp
  {
    int k2 = (1024 - tid) & 1023;
    float2 z = F[a00], mm = F[swz(k2)];
    float GAr = 0.5f * (z.x + mm.x), GAi = 0.5f * (z.y - mm.y);
    float GBr = 0.5f * (z.y + mm.y), GBi = 0.5f * (mm.x - z.x);
    float er = expf(GAr);
    float si, co;
    sincosf(GAi, &si, &co);
    hA[tid] = make_float2(er * co, er * si);
    er = expf(GBr);
    sincosf(GBi, &si, &co);
    hB[tid] = make_float2(er * co, er * si);

    z = F[a01]; mm = F[swz(768 - tid)];
    GAr = 0.5f * (z.x + mm.x); GAi = 0.5f * (z.y - mm.y);
    GBr = 0.5f * (z.y + mm.y); GBi = 0.5f * (mm.x - z.x);
    er = expf(GAr);
    sincosf(GAi, &si, &co);
    hA[tid + 256] = make_float2(er * co, er * si);
    er = expf(GBr);
    sincosf(GBi, &si, &co);
    hB[tid + 256] = make_float2(er * co, er * si);

    if (tid == 0) {
      z = F[a02];
      GAr = 0.5f * (z.x + z.x); GAi = 0.0f;
      GBr = 0.5f * (z.y + z.y); GBi = 0.0f;
      er = expf(GAr);
      sincosf(GAi, &si, &co);
      hA[512] = make_float2(er * co, er * si);
      er = expf(GBr);
      sincosf(GBi, &si, &co);
      hB[512] = make_float2(er * co, er * si);
    }
  }
  __syncthreads();

  // ---- (3) frame A ----
#define PACK_FRAME(QOFF, J, ADDR)                                      \
  {                                                                    \
    int i = tid + 256 * (J);                                           \
    int q = (QOFF) + i;                                                \
    if (q < 0) q = -q;                                                 \
    else if (q >= L_TOT) q = 2 * L_TOT - 2 - q;                        \
    float wv = hann_w(i, T0);                                          \
    F[ADDR] = make_float2(noise[q] * wv, pulse[q] * wv);               \
  }
  PACK_FRAME(256 * fA - 256, 0, a00)
  PACK_FRAME(256 * fA - 256, 1, a01)
  PACK_FRAME(256 * fA - 256, 2, a02)
  PACK_FRAME(256 * fA - 256, 3, a03)
  __syncthreads();
  { float2 t_ = T0[tid];      bfly_dif<-1>(F, a00, a01, a02, a03, t_.x, t_.y); }
  { float2 t_ = T1[tid & 63]; bfly_dif<-1>(F, a10, a11, a12, a13, t_.x, t_.y); }
  { float2 t_ = T2[tid & 15]; bfly_dif<-1>(F, a20, a21, a22, a23, t_.x, t_.y); }
  { float2 t_ = T3[tid & 3];  bfly_dif<-1>(F, a30, a31, a32, a33, t_.x, t_.y); }
  bfly_dif<-1>(F, a40, a41, a42, a43, 1.0f, 0.0f);
  float2 eA0 = *(const float2*)&envn[tid * NFR + fA];
  combine_one(tid, expf(eA0.x), F, hA);
  float2 eA1 = *(const float2*)&envn[(tid + 256) * NFR + fA];
  combine_one(tid + 256, expf(eA1.x), F, hA);
  float2 eA2 = make_float2(0.0f, 0.0f);
  if (tid == 0) {
    eA2 = *(const float2*)&envn[512 * NFR + fA];
    combine_one(512, expf(eA2.x), F, hA);
  }
  __syncthreads();

  // ---- (4) frame B ----
  PACK_FRAME(256 * fA, 0, a00)
  PACK_FRAME(256 * fA, 1, a01)
  PACK_FRAME(256 * fA, 2, a02)
  PACK_FRAME(256 * fA, 3, a03)
  __syncthreads();
  { float2 t_ = T0[tid];      bfly_dif<-1>(F, a00, a01, a02, a03, t_.x, t_.y); }
  { float2 t_ = T1[tid & 63]; bfly_dif<-1>(F, a10, a11, a12, a13, t_.x, t_.y); }
  { float2 t_ = T2[tid & 15]; bfly_dif<-1>(F, a20, a21, a22, a23, t_.x, t_.y); }
  { float2 t_ = T3[tid & 3];  bfly_dif<-1>(F, a30, a31, a32, a33, t_.x, t_.y); }
  bfly_dif<-1>(F, a40, a41, a42, a43, 1.0f, 0.0f);
  combine_one(tid, expf(eA0.y), F, hB);
  combine_one(tid + 256, expf(eA1.y), F, hB);
  if (tid == 0) combine_one(512, expf(eA2.y), F, hB);
  __syncthreads();

  // ---- (5) packed hermitian inverse ----
#pragma unroll
  for (int j = 0; j < 4; ++j) {
    int i = tid + 256 * j;
    float2 zv;
    if (i <= 512) {
      zv = make_float2(hA[i].x - hB[i].y, hA[i].y + hB[i].x);
    } else {
      int jj = 1024 - i;
      zv = make_float2(hA[jj].x + hB[jj].y, hB[jj].x - hA[jj].y);
    }
    F[swz(dr4(i))] = zv;
  }
  __syncthreads();
  bfly_dit<+1>(F, a40, a41, a42, a43, 1.0f, 0.0f);
  { float2 t_ = T3[tid & 3];  bfly_dit<+1>(F, a30, a31, a32, a33, t_.x, t_.y); }
  { float2 t_ = T2[tid & 15]; bfly_dit<+1>(F, a20, a21, a22, a23, t_.x, t_.y); }
  { float2 t_ = T1[tid & 63]; bfly_dit<+1>(F, a10, a11, a12, a13, t_.x, t_.y); }
  { float2 t_ = T0[tid];      bfly_dit<+1>(F, a00, a01, a02, a03, t_.x, t_.y); }
  // fused OLA + inline edge scaling
  const float scl = 1.0f / 1536.0f;
  {
    float2 f0v = F[a00], f1v = F[a01], f2v = F[a02], f3v = F[a03];
    float hw0 = hann_w(tid, T0) * scl;
    float hw1 = hann_w(tid + 256, T0) * scl;
    float hw2 = hann_w(tid + 512, T0) * scl;
    float hw3 = hann_w(tid + 768, T0) * scl;
    int tb = 256 * fA - 512 + tid;
    float val;
    int t;
    t = tb;
    val = f0v.x * hw0;
    if (t >= 0) {
      if (t < 256) val *= edge_scale(t, T0);
      atomicAdd(&out[t], val);
    }
    t = tb + 256;
    val = f1v.x * hw1 + f0v.y * hw0;
    if (t >= 0 && t < OUTN) {
      if (t < 256 || t >= OUTN - 256) val *= edge_scale(t, T0);
      atomicAdd(&out[t], val);
    }
    t = tb + 512;
    val = f2v.x * hw2 + f1v.y * hw1;
    if (t < OUTN) {
      if (t < 256 || t >= OUTN - 256) val *= edge_scale(t, T0);
      atomicAdd(&out[t], val);
    }
    t = tb + 768;
    val = f3v.x * hw3 + f2v.y * hw2;
    if (t < OUTN) {
      if (t >= OUTN - 256) val *= edge_scale(t, T0);
      atomicAdd(&out[t], val);
    }
    t = tb + 1024;
    val = f3v.y * hw3;
    if (t < OUTN) {
      if (t >= OUTN - 256) val *= edge_scale(t, T0);
      atomicAdd(&out[t], val);
    }
  }
#undef PACK_FRAME
}

extern "C" void kernel_launch(void* const* d_in, const int* in_sizes, int n_in,
                              void* d_out, int out_size, void* d_ws, size_t ws_size,
                              hipStream_t stream) {
  const float* logf0 = (const float*)d_in[0];
  const float* envn  = (const float*)d_in[1];
  const float* envp  = (const float*)d_in[2];
  const float* noise = (const float*)d_in[3];
  float* out = (float*)d_out;
  float* W = (float*)d_ws;

  tree_kernel<<<dim3(2048), dim3(256), 0, stream>>>(logf0, W, out);
  tree_top_kernel<<<dim3(1), dim3(256), 0, stream>>>(W);
  pulse_kernel<<<dim3(L_TOT / 4096), dim3(256), 0, stream>>>(W);
  column_kernel<<<dim3(NFR / 2), dim3(256), 0, stream>>>(noise, envn, envp, W, out);
}

// Round 8
// 225.613 us; speedup vs baseline: 2.0454x; 1.0053x over previous
//
#include <hip/hip_runtime.h>
#include <math.h>

#define L_TOT 4194304   // 2^22 upsampled samples
#define NFR   16384     // frames / f0 length
#define OUTN  4194048   // output length

// ---------- workspace layout (floats) ----------
// [0, L_TOT)                : cumsum tree level 11 only (at lvl_off(11))
// [L_TOT, 2*L_TOT)          : pulse signal
// [2*L_TOT + 0,   +512)     : twiddle cos  (cos(2*pi*j/1024))
// [2*L_TOT + 512, +1024)    : twiddle sin
// [2*L_TOT + 2048,+2048+NFR): f0 = exp(log_f0)

__device__ __forceinline__ int lvl_off(int a) {
  return L_TOT - (L_TOT >> (a - 1));
}

__device__ __forceinline__ int swz(int e) {
  int h = (e >> 4) & 3, g = (e >> 6) & 3, f = (e >> 8) & 3;
  return e ^ (h * 5) ^ (g * 3) ^ ((f * 12) & 15);
}

__device__ __forceinline__ int dr4(int p) {
  return ((p & 3) << 8) | (((p >> 2) & 3) << 6) | (((p >> 4) & 3) << 4) |
         (((p >> 6) & 3) << 2) | ((p >> 8) & 3);
}

__device__ __forceinline__ float f0_up_val(const float* f0arr, int j) {
  float pos = __fadd_rn(__fmul_rn(__fadd_rn((float)j, 0.5f), 1.0f / 256.0f), -0.5f);
  pos = fminf(fmaxf(pos, 0.0f), 16383.0f);
  int lo = (int)pos;
  int hi = min(lo + 1, NFR - 1);
  float frac = __fadd_rn(pos, -(float)lo);
  float a = __fmul_rn(f0arr[lo], __fadd_rn(1.0f, -frac));
  float b = __fmul_rn(f0arr[hi], frac);
  return __fadd_rn(a, b);
}

__device__ __forceinline__ float f0_up_local(const float* Fl, int w0, int j) {
  float pos = __fadd_rn(__fmul_rn(__fadd_rn((float)j, 0.5f), 1.0f / 256.0f), -0.5f);
  pos = fminf(fmaxf(pos, 0.0f), 16383.0f);
  int lo = (int)pos;
  int hi = min(lo + 1, NFR - 1);
  float frac = __fadd_rn(pos, -(float)lo);
  float a = __fmul_rn(Fl[lo - w0], __fadd_rn(1.0f, -frac));
  float b = __fmul_rn(Fl[hi - w0], frac);
  return __fadd_rn(a, b);
}

// ---------- cumsum tree levels 1..11 + table init + out zeroing ----------
// R6 lesson: cooperative grid.sync costs ~100-200us on MI355X (cross-XCD
// contended barrier) -- separate launches are far cheaper. This kernel
// absorbs the init_tables and memset launches. Only level 11 is written to
// HBM; pulse blocks rebuild levels 12..22 locally (bit-exact, 2047 adds).
__global__ __launch_bounds__(256) void tree_kernel(const float* __restrict__ logf0,
                                                   float* __restrict__ W,
                                                   float* __restrict__ out) {
  int tid = threadIdx.x;
  int bid = blockIdx.x;
  // global tables (low blocks)
  if (bid < 2) {
    int g = bid * 256 + tid;
    double a = (double)g * 3.14159265358979323846 / 512.0;   // 2*pi*g/1024
    W[2 * L_TOT + g] = (float)cos(a);
    W[2 * L_TOT + 512 + g] = (float)sin(a);
  }
  if (bid >= 2 && bid < 66) {
    int g = (bid - 2) * 256 + tid;
    W[2 * L_TOT + 2048 + g] = (float)exp((double)logf0[g]);  // bit-exact
  }
  // zero the output (replaces hipMemsetAsync launch): 2048 floats/block
  {
    int base_o = bid * 2048;
#pragma unroll
    for (int k = 0; k < 2; ++k) {
      int off = base_o + k * 1024 + tid * 4;
      if (off < OUTN) *(float4*)&out[off] = make_float4(0.f, 0.f, 0.f, 0.f);
    }
  }
  // tree chunk (levels 1..11)
  __shared__ float Fl[10];
  __shared__ float A[2048];
  __shared__ float B[1024];
  int base = bid * 2048;
  int w0 = (base >> 8) - 1;
  if (tid < 10) {
    int f = min(max(w0 + tid, 0), NFR - 1);
    Fl[tid] = (float)exp((double)logf0[f]);   // bit-exact vs f0arr
  }
  __syncthreads();
  for (int i = tid; i < 2048; i += 256) A[i] = f0_up_local(Fl, w0, base + i);
  __syncthreads();
  float* src = A;
  float* dst = B;
  int cnt = 1024;
  for (int a = 1; a <= 11; ++a) {
    int gbase = base >> a;
    for (int i = tid; i < cnt; i += 256) {
      float v = __fadd_rn(src[2 * i], src[2 * i + 1]);
      dst[i] = v;
      if (a == 11) W[lvl_off(11) + gbase + i] = v;
    }
    __syncthreads();
    float* tmp = src; src = dst; dst = tmp;
    cnt >>= 1;
  }
}

// top-tree prefix for m with bits only in {0, 12..22} (levels 12..22 in LDS TT)
__device__ __forceinline__ float prefix_top(const float* TT, const float* f0arr, int m) {
  float acc = 0.0f;
  bool first = true;
  int pos = 0;
  for (int a = 22; a >= 12; --a) {
    if (m & (1 << a)) {
      float node = TT[2048 - (4096 >> (a - 11)) + (pos >> a)];
      acc = first ? node : __fadd_rn(acc, node);
      first = false;
      pos += (1 << a);
    }
  }
  if (m & 1) {
    float node = f0_up_val(f0arr, pos);
    acc = first ? node : __fadd_rn(acc, node);
  }
  return acc;
}

// ---------- impulse train v3 (bit-exact; levels 12..22 rebuilt locally) ----------
__global__ __launch_bounds__(256) void pulse_kernel(float* W) {
  const float* f0arr = W + 2 * L_TOT + 2048;
  __shared__ float TT[2047];   // packed levels 12..22: off(a) = 2048 - (4096 >> (a-11))
  __shared__ float Tl[510];
  __shared__ float P[4100];
  int tid = threadIdx.x;
  int base = blockIdx.x * 4096;

  // build TT from global level 11 (P used as staging; freed after level-12 sync)
  for (int i = tid; i < 2048; i += 256) P[i] = W[lvl_off(11) + i];
  __syncthreads();
  for (int i = tid; i < 1024; i += 256) TT[i] = __fadd_rn(P[2 * i], P[2 * i + 1]);
  __syncthreads();
  {
    int off_prev = 0, cnt = 512;
    for (int a = 13; a <= 22; ++a) {
      int off = 2048 - (4096 >> (a - 11));
      for (int i = tid; i < cnt; i += 256)
        TT[off + i] = __fadd_rn(TT[off_prev + 2 * i], TT[off_prev + 2 * i + 1]);
      __syncthreads();
      off_prev = off;
      cnt >>= 1;
    }
  }

  float v[16];
#pragma unroll
  for (int c = 0; c < 16; ++c) v[c] = f0_up_val(f0arr, base + 16 * tid + c);
  float s2[8], s4[4], s8[2];
#pragma unroll
  for (int j = 0; j < 8; ++j) s2[j] = __fadd_rn(v[2 * j], v[2 * j + 1]);
#pragma unroll
  for (int j = 0; j < 4; ++j) s4[j] = __fadd_rn(s2[2 * j], s2[2 * j + 1]);
  s8[0] = __fadd_rn(s4[0], s4[1]);
  s8[1] = __fadd_rn(s4[2], s4[3]);
  Tl[tid] = __fadd_rn(s8[0], s8[1]);
  __syncthreads();
  if (tid < 128) Tl[256 + tid] = __fadd_rn(Tl[2 * tid], Tl[2 * tid + 1]);
  __syncthreads();
  if (tid < 64)  Tl[384 + tid] = __fadd_rn(Tl[256 + 2 * tid], Tl[256 + 2 * tid + 1]);
  __syncthreads();
  if (tid < 32)  Tl[448 + tid] = __fadd_rn(Tl[384 + 2 * tid], Tl[384 + 2 * tid + 1]);
  __syncthreads();
  if (tid < 16)  Tl[480 + tid] = __fadd_rn(Tl[448 + 2 * tid], Tl[448 + 2 * tid + 1]);
  __syncthreads();
  if (tid < 8)   Tl[496 + tid] = __fadd_rn(Tl[480 + 2 * tid], Tl[480 + 2 * tid + 1]);
  __syncthreads();
  if (tid < 4)   Tl[504 + tid] = __fadd_rn(Tl[496 + 2 * tid], Tl[496 + 2 * tid + 1]);
  __syncthreads();
  if (tid < 2)   Tl[508 + tid] = __fadd_rn(Tl[504 + 2 * tid], Tl[504 + 2 * tid + 1]);
  __syncthreads();

  // top fold (levels 22..12 of base) — from local TT (bit-exact vs W walk)
  float accT = 0.0f;
  bool firstT = true;
  {
    int pos = 0;
    for (int a = 22; a >= 12; --a) {
      if (base & (1 << a)) {
        float node = TT[2048 - (4096 >> (a - 11)) + (pos >> a)];
        accT = firstT ? node : __fadd_rn(accT, node);
        firstT = false;
        pos += (1 << a);
      }
    }
  }
  float accM = accT;
  bool firstM = firstT;
  {
    int rh = 16 * tid;
    int lpos = 0;
    for (int a = 11; a >= 4; --a) {
      if (rh & (1 << a)) {
        float node = Tl[512 - (512 >> (a - 4)) + (lpos >> a)];
        accM = firstM ? node : __fadd_rn(accM, node);
        firstM = false;
        lpos += (1 << a);
      }
    }
  }
  if (tid >= 1) P[16 * tid] = accM;
#pragma unroll
  for (int c = 1; c <= 15; ++c) {
    float acc = accM;
    bool first = firstM;
    int lp = 0;
    if (c & 8) { float n = s8[lp >> 3]; acc = first ? n : __fadd_rn(acc, n); first = false; lp += 8; }
    if (c & 4) { float n = s4[lp >> 2]; acc = first ? n : __fadd_rn(acc, n); first = false; lp += 4; }
    if (c & 2) { float n = s2[lp >> 1]; acc = first ? n : __fadd_rn(acc, n); first = false; lp += 2; }
    if (c & 1) { float n = v[lp];       acc = first ? n : __fadd_rn(acc, n); }
    P[16 * tid + c] = acc;
  }
  if (tid == 0) P[4096] = prefix_top(TT, f0arr, base + 4096);
  if (tid == 1) {
    int m2 = base + 4097;
    P[4097] = (m2 <= L_TOT) ? prefix_top(TT, f0arr, m2) : 0.0f;
  }
  __syncthreads();

  float o[16];
#pragma unroll
  for (int c = 0; c < 16; ++c) {
    int i = base + 16 * tid + c;
    float P1 = P[16 * tid + c + 1];
    float P2 = (i == L_TOT - 1) ? f0_up_val(f0arr, 0)   // prefix_sum(1) == f0_up(0)
                                : P[16 * tid + c + 2];
    float t1 = __fdiv_rn(P1, 24000.0f);
    float saw1 = __fadd_rn(t1, -floorf(t1));
    float t2 = __fdiv_rn(P2, 24000.0f);
    float saw2 = __fadd_rn(t2, -floorf(t2));
    float cc = __fdiv_rn(v[c], 24000.0f);
    o[c] = __fadd_rn(__fadd_rn(saw1, -saw2), cc);
  }
#pragma unroll
  for (int k = 0; k < 4; ++k)
    *(float4*)&W[L_TOT + base + 16 * tid + 4 * k] =
        make_float4(o[4 * k], o[4 * k + 1], o[4 * k + 2], o[4 * k + 3]);
}

// ---------- in-place radix-4 butterflies, precomputed swizzled addresses ----------
template <int DIR>
__device__ __forceinline__ void bfly_dif(float2* F, int e0, int e1, int e2, int e3,
                                         float ur, float ui) {
  if (DIR < 0) ui = -ui;
  float2 x0 = F[e0], x1 = F[e1], x2 = F[e2], x3 = F[e3];
  float s0r = x0.x + x2.x, s0i = x0.y + x2.y;
  float s1r = x1.x + x3.x, s1i = x1.y + x3.y;
  float d0r = x0.x - x2.x, d0i = x0.y - x2.y;
  float ddr = x1.x - x3.x, ddi = x1.y - x3.y;
  float t3r = (DIR > 0) ? -ddi : ddi;
  float t3i = (DIR > 0) ? ddr : -ddr;
  float vr = ur * ur - ui * ui, vi = 2.0f * ur * ui;
  float w3r = ur * vr - ui * vi, w3i = ur * vi + ui * vr;
  F[e0] = make_float2(s0r + s1r, s0i + s1i);
  float a1r = d0r + t3r, a1i = d0i + t3i;
  F[e1] = make_float2(a1r * ur - a1i * ui, a1r * ui + a1i * ur);
  float a2r = s0r - s1r, a2i = s0i - s1i;
  F[e2] = make_float2(a2r * vr - a2i * vi, a2r * vi + a2i * vr);
  float a3r = d0r - t3r, a3i = d0i - t3i;
  F[e3] = make_float2(a3r * w3r - a3i * w3i, a3r * w3i + a3i * w3r);
  __syncthreads();
}

template <int DIR>
__device__ __forceinline__ void bfly_dit(float2* F, int e0, int e1, int e2, int e3,
                                         float ur, float ui) {
  if (DIR < 0) ui = -ui;
  float2 x0 = F[e0], x1 = F[e1], x2 = F[e2], x3 = F[e3];
  float vr = ur * ur - ui * ui, vi = 2.0f * ur * ui;
  float w3r = ur * vr - ui * vi, w3i = ur * vi + ui * vr;
  float b1r = x1.x * ur - x1.y * ui, b1i = x1.x * ui + x1.y * ur;
  float b2r = x2.x * vr - x2.y * vi, b2i = x2.x * vi + x2.y * vr;
  float b3r = x3.x * w3r - x3.y * w3i, b3i = x3.x * w3i + x3.y * w3r;
  float s0r = x0.x + b2r, s0i = x0.y + b2i;
  float d0r = x0.x - b2r, d0i = x0.y - b2i;
  float s1r = b1r + b3r, s1i = b1i + b3i;
  float ddr = b1r - b3r, ddi = b1i - b3i;
  float d1r = (DIR > 0) ? -ddi : ddi;
  float d1i = (DIR > 0) ? ddr : -ddr;
  F[e0] = make_float2(s0r + s1r, s0i + s1i);
  F[e1] = make_float2(d0r + d1r, d0i + d1i);
  F[e2] = make_float2(s0r - s1r, s0i - s1i);
  F[e3] = make_float2(d0r - d1r, d0i - d1i);
  __syncthreads();
}

__device__ __forceinline__ float hann_w(int i, const float2* T0) {
  int j = (i > 512) ? (1024 - i) : i;
  float c = (j <= 256) ? T0[j].x : -T0[512 - j].x;
  return 0.5f - 0.5f * c;
}

__device__ __forceinline__ float edge_scale(int t, const float2* T0) {
  int p = t + 512;
  int jmin = max(0, (p - 768) >> 8);
  int jmax = min(NFR - 1, p >> 8);
  float wsq = 0.0f;
  for (int j = jmin; j <= jmax; ++j) {
    float w = hann_w(p - 256 * j, T0);
    wsq += w * w;
  }
  return 1.5f / fmaxf(wsq, 1e-11f);
}

__device__ __forceinline__ void combine_one(int k, float An, const float2* F, float2* H) {
  int k2 = (1024 - k) & 1023;
  float2 z = F[swz(dr4(k))], mm = F[swz(dr4(k2))];
  float Ar = 0.5f * (z.x + mm.x), Ai = 0.5f * (z.y - mm.y);
  float Br = 0.5f * (z.y + mm.y), Bi = 0.5f * (mm.x - z.x);
  float2 h = H[k];
  H[k] = make_float2(Br * h.x - Bi * h.y + Ar * An,
                     Br * h.y + Bi * h.x + Ai * An);
}

// ---------- per-block fused kernel: TWO adjacent frames, 5 in-place FFTs ----------
__global__ __launch_bounds__(256) void column_kernel(
    const float* __restrict__ noise,
    const float* __restrict__ envn,
    const float* __restrict__ envp,
    const float* __restrict__ W,
    float* __restrict__ out) {
  __shared__ float2 F[1024];
  __shared__ float2 hA[513], hB[513];
  __shared__ float2 TW[341];
  int tid = threadIdx.x;
  int bid = blockIdx.x;
  int g = (bid & 7) * 1024 + (bid >> 3);
  int fA = 2 * g;
  const float* pulse = W + L_TOT;
  const float* gtab = W + 2 * L_TOT;
  const float2* T0 = TW;
  const float2* T1 = TW + 257;
  const float2* T2 = TW + 321;
  const float2* T3 = TW + 337;

  for (int i = tid; i < 341; i += 256) {
    int e;
    if (i < 257) e = i;
    else if (i < 321) e = (i - 257) << 2;
    else if (i < 337) e = (i - 321) << 4;
    else e = (i - 337) << 6;
    TW[i] = make_float2(gtab[e], gtab[512 + e]);
  }
  for (int k = tid; k < 513; k += 256) {
    float2 e = *(const float2*)&envp[k * NFR + fA];
    hA[k] = e;
  }

  int a00 = swz(tid), a01 = swz(tid + 256), a02 = swz(tid + 512), a03 = swz(tid + 768);
  int b1_ = ((tid >> 6) << 8) | (tid & 63);
  int a10 = swz(b1_), a11 = swz(b1_ + 64), a12 = swz(b1_ + 128), a13 = swz(b1_ + 192);
  int b2_ = ((tid >> 4) << 6) | (tid & 15);
  int a20 = swz(b2_), a21 = swz(b2_ + 16), a22 = swz(b2_ + 32), a23 = swz(b2_ + 48);
  int b3_ = ((tid >> 2) << 4) | (tid & 3);
  int a30 = swz(b3_), a31 = swz(b3_ + 4), a32 = swz(b3_ + 8), a33 = swz(b3_ + 12);
  int q_ = tid << 2;
  int a40 = swz(q_), a41 = swz(q_ + 1), a42 = swz(q_ + 2), a43 = swz(q_ + 3);
  __syncthreads();

  // ---- (1) packed cepstrum ----
  F[a00] = hA[tid];
  F[a01] = hA[tid + 256];
  F[a02] = (tid == 0) ? hA[512] : hA[512 - tid];
  F[a03] = hA[256 - tid];
  __syncthreads();
  { float2 t_ = T0[tid];      bfly_dif<+1>(F, a00, a01, a02, a03, t_.x, t_.y); }
  { float2 t_ = T1[tid & 63]; bfly_dif<+1>(F, a10, a11, a12, a13, t_.x, t_.y); }
  { float2 t_ = T2[tid & 15]; bfly_dif<+1>(F, a20, a21, a22, a23, t_.x, t_.y); }
  { float2 t_ = T3[tid & 3];  bfly_dif<+1>(F, a30, a31, a32, a33, t_.x, t_.y); }
  // register phase: DIF s4 + cep fold + DIT<-1> s0 on thread-local {4t..4t+3}
  {
    int drt = ((tid & 3) << 6) | (((tid >> 2) & 3) << 4) |
              (((tid >> 4) & 3) << 2) | ((tid >> 6) & 3);   // dr4(4*tid)
    float2 x0 = F[a40], x1 = F[a41], x2 = F[a42], x3 = F[a43];
    float s0r = x0.x + x2.x, s0i = x0.y + x2.y;
    float s1r = x1.x + x3.x, s1i = x1.y + x3.y;
    float d0r = x0.x - x2.x, d0i = x0.y - x2.y;
    float ddr = x1.x - x3.x, ddi = x1.y - x3.y;
    float y0r = s0r + s1r, y0i = s0i + s1i;       // bin drt
    float y1r = d0r - ddi, y1i = d0i + ddr;       // bin drt+256
    float y2r = s0r - s1r, y2i = s0i - s1i;       // bin drt+512
    float sc0 = (drt == 0) ? (1.0f / 1024.0f) : (2.0f / 1024.0f);
    float sc2 = (drt == 0) ? (1.0f / 1024.0f) : 0.0f;
    y0r *= sc0; y0i *= sc0;
    y1r *= (2.0f / 1024.0f); y1i *= (2.0f / 1024.0f);
    y2r *= sc2; y2i *= sc2;
    float S0r = y0r + y2r, S0i = y0i + y2i;
    float D0r = y0r - y2r, D0i = y0i - y2i;
    float D1r = y1i, D1i = -y1r;                  // DIR=-1, dd=y1
    F[a40] = make_float2(S0r + y1r, S0i + y1i);
    F[a41] = make_float2(D0r + D1r, D0i + D1i);
    F[a42] = make_float2(S0r - y1r, S0i - y1i);
    F[a43] = make_float2(D0r - D1r, D0i - D1i);
  }
  __syncthreads();
  { float2 t_ = T3[tid & 3];  bfly_dit<-1>(F, a30, a31, a32, a33, t_.x, t_.y); }
  { float2 t_ = T2[tid & 15]; bfly_dit<-1>(F, a20, a21, a22, a23, t_.x, t_.y); }
  { float2 t_ = T1[tid & 63]; bfly_dit<-1>(F, a10, a11, a12, a13, t_.x, t_.y); }
  { float2 t_ = T0[tid];      bfly_dit<-1>(F, a00, a01, a02, a03, t_.x, t_.y); }
  // hermitian unpack; H=exp
  {
    int k2 = (1024 - tid) & 1023;
    float2 z = F[a00], mm = F[swz(k2)];
    float GAr = 0.5f * (z.x + mm.x), GAi = 0.5f * (z.y - mm.y);
    float GBr = 0.5f * (z.y + mm.y), GBi = 0.5f * (mm.x - z.x);
    float er = expf(GAr);
    float si, co;
    sincosf(GAi, &si, &co);
    hA[tid] = make_float2(er * co, er * si);
    er = expf(GBr);
    sincosf(GBi, &si, &co);
    hB[tid] = make_float2(er * co, er * si);

    z = F[a01]; mm = F[swz(768 - tid)];
    GAr = 0.5f * (z.x + mm.x); GAi = 0.5f * (z.y - mm.y);
    GBr = 0.5f * (z.y + mm.y); GBi = 0.5f * (mm.x - z.x);
    er = expf(GAr);
    sincosf(GAi, &si, &co);
    hA[tid + 256] = make_float2(er * co, er * si);
    er = expf(GBr);
    sincosf(GBi, &si, &co);
    hB[tid + 256] = make_float2(er * co, er * si);

    if (tid == 0) {
      z = F[a02];
      GAr = 0.5f * (z.x + z.x); GAi = 0.0f;
      GBr = 0.5f * (z.y + z.y); GBi = 0.0f;
      er = expf(GAr);
      sincosf(GAi, &si, &co);
      hA[512] = make_float2(er * co, er * si);
      er = expf(GBr);
      sincosf(GBi, &si, &co);
      hB[512] = make_float2(er * co, er * si);
    }
  }
  __syncthreads();

  // ---- (3) frame A ----
#define PACK_FRAME(QOFF, J, ADDR)                                      \
  {                                                                    \
    int i = tid + 256 * (J);                                           \
    int q = (QOFF) + i;                                                \
    if (q < 0) q = -q;                                                 \
    else if (q >= L_TOT) q = 2 * L_TOT - 2 - q;                        \
    float wv = hann_w(i, T0);                                          \
    F[ADDR] = make_float2(noise[q] * wv, pulse[q] * wv);               \
  }
  PACK_FRAME(256 * fA - 256, 0, a00)
  PACK_FRAME(256 * fA - 256, 1, a01)
  PACK_FRAME(256 * fA - 256, 2, a02)
  PACK_FRAME(256 * fA - 256, 3, a03)
  __syncthreads();
  { float2 t_ = T0[tid];      bfly_dif<-1>(F, a00, a01, a02, a03, t_.x, t_.y); }
  { float2 t_ = T1[tid & 63]; bfly_dif<-1>(F, a10, a11, a12, a13, t_.x, t_.y); }
  { float2 t_ = T2[tid & 15]; bfly_dif<-1>(F, a20, a21, a22, a23, t_.x, t_.y); }
  { float2 t_ = T3[tid & 3];  bfly_dif<-1>(F, a30, a31, a32, a33, t_.x, t_.y); }
  bfly_dif<-1>(F, a40, a41, a42, a43, 1.0f, 0.0f);
  float2 eA0 = *(const float2*)&envn[tid * NFR + fA];
  combine_one(tid, expf(eA0.x), F, hA);
  float2 eA1 = *(const float2*)&envn[(tid + 256) * NFR + fA];
  combine_one(tid + 256, expf(eA1.x), F, hA);
  float2 eA2 = make_float2(0.0f, 0.0f);
  if (tid == 0) {
    eA2 = *(const float2*)&envn[512 * NFR + fA];
    combine_one(512, expf(eA2.x), F, hA);
  }
  __syncthreads();

  // ---- (4) frame B ----
  PACK_FRAME(256 * fA, 0, a00)
  PACK_FRAME(256 * fA, 1, a01)
  PACK_FRAME(256 * fA, 2, a02)
  PACK_FRAME(256 * fA, 3, a03)
  __syncthreads();
  { float2 t_ = T0[tid];      bfly_dif<-1>(F, a00, a01, a02, a03, t_.x, t_.y); }
  { float2 t_ = T1[tid & 63]; bfly_dif<-1>(F, a10, a11, a12, a13, t_.x, t_.y); }
  { float2 t_ = T2[tid & 15]; bfly_dif<-1>(F, a20, a21, a22, a23, t_.x, t_.y); }
  { float2 t_ = T3[tid & 3];  bfly_dif<-1>(F, a30, a31, a32, a33, t_.x, t_.y); }
  bfly_dif<-1>(F, a40, a41, a42, a43, 1.0f, 0.0f);
  combine_one(tid, expf(eA0.y), F, hB);
  combine_one(tid + 256, expf(eA1.y), F, hB);
  if (tid == 0) combine_one(512, expf(eA2.y), F, hB);
  __syncthreads();

  // ---- (5) packed hermitian inverse ----
#pragma unroll
  for (int j = 0; j < 4; ++j) {
    int i = tid + 256 * j;
    float2 zv;
    if (i <= 512) {
      zv = make_float2(hA[i].x - hB[i].y, hA[i].y + hB[i].x);
    } else {
      int jj = 1024 - i;
      zv = make_float2(hA[jj].x + hB[jj].y, hB[jj].x - hA[jj].y);
    }
    F[swz(dr4(i))] = zv;
  }
  __syncthreads();
  bfly_dit<+1>(F, a40, a41, a42, a43, 1.0f, 0.0f);
  { float2 t_ = T3[tid & 3];  bfly_dit<+1>(F, a30, a31, a32, a33, t_.x, t_.y); }
  { float2 t_ = T2[tid & 15]; bfly_dit<+1>(F, a20, a21, a22, a23, t_.x, t_.y); }
  { float2 t_ = T1[tid & 63]; bfly_dit<+1>(F, a10, a11, a12, a13, t_.x, t_.y); }
  { float2 t_ = T0[tid];      bfly_dit<+1>(F, a00, a01, a02, a03, t_.x, t_.y); }
  // fused OLA + inline edge scaling
  const float scl = 1.0f / 1536.0f;
  {
    float2 f0v = F[a00], f1v = F[a01], f2v = F[a02], f3v = F[a03];
    float hw0 = hann_w(tid, T0) * scl;
    float hw1 = hann_w(tid + 256, T0) * scl;
    float hw2 = hann_w(tid + 512, T0) * scl;
    float hw3 = hann_w(tid + 768, T0) * scl;
    int tb = 256 * fA - 512 + tid;
    float val;
    int t;
    t = tb;
    val = f0v.x * hw0;
    if (t >= 0) {
      if (t < 256) val *= edge_scale(t, T0);
      atomicAdd(&out[t], val);
    }
    t = tb + 256;
    val = f1v.x * hw1 + f0v.y * hw0;
    if (t >= 0 && t < OUTN) {
      if (t < 256 || t >= OUTN - 256) val *= edge_scale(t, T0);
      atomicAdd(&out[t], val);
    }
    t = tb + 512;
    val = f2v.x * hw2 + f1v.y * hw1;
    if (t < OUTN) {
      if (t < 256 || t >= OUTN - 256) val *= edge_scale(t, T0);
      atomicAdd(&out[t], val);
    }
    t = tb + 768;
    val = f3v.x * hw3 + f2v.y * hw2;
    if (t < OUTN) {
      if (t >= OUTN - 256) val *= edge_scale(t, T0);
      atomicAdd(&out[t], val);
    }
    t = tb + 1024;
    val = f3v.y * hw3;
    if (t < OUTN) {
      if (t >= OUTN - 256) val *= edge_scale(t, T0);
      atomicAdd(&out[t], val);
    }
  }
#undef PACK_FRAME
}

extern "C" void kernel_launch(void* const* d_in, const int* in_sizes, int n_in,
                              void* d_out, int out_size, void* d_ws, size_t ws_size,
                              hipStream_t stream) {
  const float* logf0 = (const float*)d_in[0];
  const float* envn  = (const float*)d_in[1];
  const float* envp  = (const float*)d_in[2];
  const float* noise = (const float*)d_in[3];
  float* out = (float*)d_out;
  float* W = (float*)d_ws;

  tree_kernel<<<dim3(2048), dim3(256), 0, stream>>>(logf0, W, out);
  pulse_kernel<<<dim3(L_TOT / 4096), dim3(256), 0, stream>>>(W);
  column_kernel<<<dim3(NFR / 2), dim3(256), 0, stream>>>(noise, envn, envp, W, out);
}